// Round 4
// baseline (151.827 us; speedup 1.0000x reference)
//
#include <hip/hip_runtime.h>
#include <math.h>

#define T_DIM 2048
#define C_DIM 1024
#define H_DIM 64
#define M_TOTAL 16384            // B*T
#define NQKV 192                 // k(0..63) | q(64..127) | v(128..191)

typedef __bf16 bf16x8 __attribute__((ext_vector_type(8)));
typedef float f32x4 __attribute__((ext_vector_type(4)));
typedef float f32x2 __attribute__((ext_vector_type(2)));
typedef unsigned short u16x8 __attribute__((ext_vector_type(8)));

#if __has_builtin(__builtin_amdgcn_fdot2_f32_bf16)
#define HAVE_DOT2 1
typedef __bf16 bf16x2 __attribute__((ext_vector_type(2)));
#else
#define HAVE_DOT2 0
#endif

__device__ __forceinline__ unsigned short f2bf(float f) {
    unsigned u = __float_as_uint(f);
    unsigned r = (u + 0x7FFFu + ((u >> 16) & 1u)) >> 16;   // RNE
    return (unsigned short)r;
}
__device__ __forceinline__ float bf2f(unsigned short u) {
    return __uint_as_float(((unsigned)u) << 16);
}
__device__ __forceinline__ float blo(unsigned u) { return __uint_as_float(u << 16); }
__device__ __forceinline__ float bhi(unsigned u) { return __uint_as_float(u & 0xFFFF0000u); }
__device__ __forceinline__ unsigned pack_bf2(float f0, float f1) {
    unsigned u0 = __float_as_uint(f0) + 0x8000u;
    unsigned u1 = __float_as_uint(f1) + 0x8000u;
    return __builtin_amdgcn_perm(u1, u0, 0x07060302u);
}
__device__ __forceinline__ uint4 cvt8(float4 a, float4 b) {
    return make_uint4(pack_bf2(a.x, a.y), pack_bf2(a.z, a.w),
                      pack_bf2(b.x, b.y), pack_bf2(b.z, b.w));
}

// 8-elem bf16 dot: v_dot2_f32_bf16 when available, fma fallback.
__device__ __forceinline__ float dot8bf(u16x8 a, u16x8 b, float c) {
#if HAVE_DOT2
    bf16x8 av = __builtin_bit_cast(bf16x8, a);
    bf16x8 bv = __builtin_bit_cast(bf16x8, b);
    #pragma unroll
    for (int e = 0; e < 4; ++e) {
        bf16x2 ap = {av[2 * e], av[2 * e + 1]};
        bf16x2 bp = {bv[2 * e], bv[2 * e + 1]};
        c = __builtin_amdgcn_fdot2_f32_bf16(ap, bp, c, false);
    }
#else
    #pragma unroll
    for (int e = 0; e < 8; ++e) c = fmaf(bf2f(a[e]), bf2f(b[e]), c);
#endif
    return c;
}

// ---------------------------------------------------------------------------
// DPP cross-lane (VALU pipe). 0xB1=xor1, 0x4E=xor2, 0x141=row_half_mirror
// (==xor4 on 4-uniform data). Validated end-to-end by R10/R12 passing runs.
// ---------------------------------------------------------------------------
#if __has_builtin(__builtin_amdgcn_update_dpp)
#define HAVE_DPP 1
template<int CTRL>
__device__ __forceinline__ float dppf(float x) {
    int v = __builtin_amdgcn_update_dpp(0, __builtin_bit_cast(int, x),
                                        CTRL, 0xF, 0xF, true);
    return __builtin_bit_cast(float, v);
}
__device__ __forceinline__ float red8(float p) {          // sum over 8-lane group
    p += dppf<0xB1>(p);
    p += dppf<0x4E>(p);
    p += dppf<0x141>(p);
    return p;
}
#else
#define HAVE_DPP 0
__device__ __forceinline__ float red8(float p) {
    p += __shfl_xor(p, 1); p += __shfl_xor(p, 2); p += __shfl_xor(p, 4);
    return p;
}
#endif

// ---------------------------------------------------------------------------
// Kernel 0: per-row random dedup + compaction (R10-validated, unchanged).
// ---------------------------------------------------------------------------
__global__ __launch_bounds__(256) void compact_kernel(
    const int* __restrict__ rnd,          // [2048][64]
    int* __restrict__ rjc,                // [2048][64]
    int* __restrict__ nvalb)              // [2048]
{
    __shared__ unsigned bm_all[4][64];
    const int wv = threadIdx.x >> 6;
    const int ln = threadIdx.x & 63;
    const int i  = blockIdx.x * 4 + wv;
    unsigned* bm = bm_all[wv];

    bm[ln] = 0u;
    int  j2 = rnd[i * 64 + ln];
    bool v2 = (j2 < i - 63) && (j2 >= 64);
    if (v2) {   // dedup: winner of atomicOr keeps the column
        unsigned old = atomicOr(&bm[j2 >> 5], 1u << (j2 & 31));
        v2 = ((old >> (j2 & 31)) & 1u) == 0u;
    }
    unsigned long long mbal = __ballot(v2);
    const int nval = __popcll(mbal);
    if (v2) {
        int pos = __popcll(mbal & ((1ull << ln) - 1ull));
        rjc[i * 64 + pos] = j2;
    }
    if (ln >= nval) rjc[i * 64 + ln] = 0;   // safe pad (disjoint addresses)
    if (ln == 0) nvalb[i] = nval;
}

// ---------------------------------------------------------------------------
// Kernel 1: fused convert + bf16 MFMA QKV projection (unchanged).
// ---------------------------------------------------------------------------
__global__ __launch_bounds__(512) void proj_kernel(
    const float* __restrict__ x,
    const float* __restrict__ Wk,
    const float* __restrict__ Wq,
    const float* __restrict__ Wv,
    unsigned short* __restrict__ qkv)   // [16384][192] bf16 bits
{
    __shared__ unsigned short Ab[64 * 64];    // [row][k^swz]
    __shared__ unsigned short Bb[192 * 64];   // [col][k^swz]

    const int m0 = blockIdx.x * 64;
    const int t  = threadIdx.x;
    const int wv = t >> 6, ln = t & 63;
    const int mfr = ln & 15, kq = ln >> 4;
    const int r0 = (wv & 1) * 32;
    const int c0 = (wv >> 1) * 48;

    const int srow  = t >> 3;                // 0..63
    const int sk8   = (t & 7) * 8;
    const int skoff = sk8 ^ ((srow & 7) * 8);

    const float* gp[4] = {
        x  + (size_t)(m0 + srow) * C_DIM + sk8,
        Wk + (size_t)srow * C_DIM + sk8,
        Wq + (size_t)srow * C_DIM + sk8,
        Wv + (size_t)srow * C_DIM + sk8 };
    unsigned short* lp[4] = {
        &Ab[srow * 64 + skoff],
        &Bb[srow * 64 + skoff],
        &Bb[(srow + 64) * 64 + skoff],
        &Bb[(srow + 128) * 64 + skoff] };

    f32x4 acc[2][3] = {};

    float4 ra[4], rb[4];
    #pragma unroll
    for (int s = 0; s < 4; ++s) {
        ra[s] = *(const float4*)(gp[s]);
        rb[s] = *(const float4*)(gp[s] + 4);
    }

    for (int kc = 0; kc < C_DIM; kc += 64) {
        __syncthreads();
        #pragma unroll
        for (int s = 0; s < 4; ++s)
            *(uint4*)lp[s] = cvt8(ra[s], rb[s]);
        if (kc + 64 < C_DIM) {
            #pragma unroll
            for (int s = 0; s < 4; ++s) {
                ra[s] = *(const float4*)(gp[s] + kc + 64);
                rb[s] = *(const float4*)(gp[s] + kc + 68);
            }
        }
        __syncthreads();
        #pragma unroll
        for (int ks = 0; ks < 64; ks += 32) {
            bf16x8 af[2], bf[3];
            #pragma unroll
            for (int a = 0; a < 2; ++a) {
                int row = r0 + a * 16 + mfr;
                af[a] = *(const bf16x8*)&Ab[row * 64 + ((ks + kq * 8) ^ ((row & 7) * 8))];
            }
            #pragma unroll
            for (int b2 = 0; b2 < 3; ++b2) {
                int row = c0 + b2 * 16 + mfr;
                bf[b2] = *(const bf16x8*)&Bb[row * 64 + ((ks + kq * 8) ^ ((row & 7) * 8))];
            }
            #pragma unroll
            for (int a = 0; a < 2; ++a)
                #pragma unroll
                for (int b2 = 0; b2 < 3; ++b2)
                    acc[a][b2] = __builtin_amdgcn_mfma_f32_16x16x32_bf16(
                        af[a], bf[b2], acc[a][b2], 0, 0, 0);
        }
    }

    #pragma unroll
    for (int a = 0; a < 2; ++a)
        #pragma unroll
        for (int b2 = 0; b2 < 3; ++b2)
            #pragma unroll
            for (int r = 0; r < 4; ++r) {
                int row = m0 + r0 + a * 16 + kq * 4 + r;
                int col = c0 + b2 * 16 + mfr;
                qkv[(size_t)row * NQKV + col] = f2bf(acc[a][b2][r]);
            }
}

// ---------------------------------------------------------------------------
// Kernel 2: sparse BigBird attention — R13: fully register-resident scores.
// Observation: slot s = idx*8 + gg is BOTH computed (QK) and consumed (PV)
// by row-group gg, so scores never cross lanes. All 24 per-group scores live
// in p[24] (compile-time indexed -> VGPRs). Softmax in-register: local
// max/sum over 24 + shfl_xor(8/16/32) across the 8 groups (within a group
// all 8 lanes hold identical values after red8). Invalid slots masked to
// -1e30 -> __expf underflows to exact 0 == R12's zero-weight-pad semantics.
// No LDS at all; gather layout (R9, row-group in HIGH lane bits -> 8
// consecutive lanes read one contiguous 128B row) unchanged; guard structure
// (nval>0 / nval>32 wave-uniform batches) unchanged from R12.
// ---------------------------------------------------------------------------
__global__ __launch_bounds__(256) void attn_kernel(
    const unsigned short* __restrict__ qkv,   // bf16 bits [16384][192]
    const int*  __restrict__ rjc,             // [2048][64] compacted randoms
    const int*  __restrict__ nvalb,           // [2048]
    float* __restrict__ out)                  // [16384][64]
{
    const int wv = threadIdx.x >> 6;
    const int ln = threadIdx.x & 63;
    const int b  = blockIdx.x & 7;                  // XCD-locality swizzle
    const int i  = ((blockIdx.x >> 3) << 2) + wv;   // 0..2047
    const int bi = b * T_DIM + i;

    const int  nval = nvalb[i];                     // wave-uniform
    const int* rji  = rjc + i * 64;

    // ---- layout: gg = ln>>3 row-group (HIGH bits of slot), 8 lanes/row ----
    const int e8 = (ln & 7) * 8;     // h-slice base for this lane
    const int gg = ln >> 3;          // row-group 0..7
    u16x8 qraw = *(const u16x8*)(qkv + (size_t)bi * NQKV + 64 + e8);
    const unsigned short* kb = qkv + (size_t)b * T_DIM * NQKV;

    // scores for this lane's group: slot s = idx*8 + gg, idx = 0..23
    float p[24];
    #pragma unroll
    for (int idx = 16; idx < 24; ++idx) p[idx] = 0.f;  // unexecuted rand slots

    // ---- QK locals+globals: idx 0..15 in 4-wide batches ----
    #pragma unroll
    for (int n = 0; n < 16; n += 4) {
        int jj[4];
        #pragma unroll
        for (int u = 0; u < 4; ++u) {
            int s = (n + u) * 8 + gg;
            int j;
            if (s < 64) { j = i - s; j = (j < 0) ? 0 : j; }
            else        { j = s - 64; }
            jj[u] = j;
        }
        u16x8 kvv[4];
        #pragma unroll
        for (int u = 0; u < 4; ++u)
            kvv[u] = *(const u16x8*)(kb + (size_t)jj[u] * NQKV + e8);
        #pragma unroll
        for (int u = 0; u < 4; ++u)
            p[n + u] = red8(dot8bf(kvv[u], qraw, 0.f));
    }

    // ---- QK randoms: compacted, wave-uniform guarded ----
    auto qk_rand = [&](int n0) {   // n0 in {16,20}: random idx (n0-16)*8 .. +31
        int jj[4];
        #pragma unroll
        for (int u = 0; u < 4; ++u) jj[u] = rji[(n0 - 16 + u) * 8 + gg];
        u16x8 kvv[4];
        #pragma unroll
        for (int u = 0; u < 4; ++u)
            kvv[u] = *(const u16x8*)(kb + (size_t)jj[u] * NQKV + e8);
        #pragma unroll
        for (int u = 0; u < 4; ++u)
            p[n0 + u] = red8(dot8bf(kvv[u], qraw, 0.f));
    };
    if (nval > 0)  qk_rand(16);
    if (nval > 32) qk_rand(20);

    // ---- mask + scale in place (invalid -> -1e30) ----
    #pragma unroll
    for (int idx = 0; idx < 8; ++idx) {
        bool v = (idx * 8 + gg) <= i;               // local col i-s >= 0
        p[idx] = v ? p[idx] * 0.125f : -1e30f;
    }
    #pragma unroll
    for (int idx = 8; idx < 16; ++idx) {
        bool v = ((idx - 8) * 8 + gg) < (i - 63);   // global col < i-63
        p[idx] = v ? p[idx] * 0.125f : -1e30f;
    }
    #pragma unroll
    for (int idx = 16; idx < 24; ++idx) {
        bool v = ((idx - 16) * 8 + gg) < nval;      // compacted random valid
        p[idx] = v ? p[idx] * 0.125f : -1e30f;
    }

    // ---- softmax, fully in-register + 3 shfl per reduction ----
    float mx = p[0];
    #pragma unroll
    for (int idx = 1; idx < 24; ++idx) mx = fmaxf(mx, p[idx]);
    mx = fmaxf(mx, __shfl_xor(mx, 8));
    mx = fmaxf(mx, __shfl_xor(mx, 16));
    mx = fmaxf(mx, __shfl_xor(mx, 32));

    float sum = 0.f;
    #pragma unroll
    for (int idx = 0; idx < 24; ++idx) {
        p[idx] = __expf(p[idx] - mx);   // masked slots underflow to exact 0
        sum += p[idx];
    }
    sum += __shfl_xor(sum, 8);
    sum += __shfl_xor(sum, 16);
    sum += __shfl_xor(sum, 32);

    // ---- PV locals+globals: 2 batches of 8, weights straight from p[] ----
    const unsigned short* vb = kb + 128;
    f32x2 acc2[4] = {};
    #pragma unroll
    for (int bt = 0; bt < 2; ++bt) {
        int jc[8];
        #pragma unroll
        for (int c = 0; c < 8; ++c) {
            int s = (bt * 8 + c) * 8 + gg;
            int j;
            if (s < 64) { j = i - s; j = (j < 0) ? 0 : j; }
            else        { j = s - 64; }
            jc[c] = j;
        }
        uint4 vv[8];
        #pragma unroll
        for (int c = 0; c < 8; ++c)
            vv[c] = *(const uint4*)(vb + (size_t)jc[c] * NQKV + e8);
        #pragma unroll
        for (int c = 0; c < 8; ++c) {
            float w = p[bt * 8 + c];
            f32x2 w2 = {w, w};
            f32x2 p0 = {blo(vv[c].x), bhi(vv[c].x)};
            f32x2 p1 = {blo(vv[c].y), bhi(vv[c].y)};
            f32x2 p2 = {blo(vv[c].z), bhi(vv[c].z)};
            f32x2 p3 = {blo(vv[c].w), bhi(vv[c].w)};
            acc2[0] += w2 * p0;
            acc2[1] += w2 * p1;
            acc2[2] += w2 * p2;
            acc2[3] += w2 * p3;
        }
    }
    // ---- PV randoms: guarded 4-wide batches, weights from p[16..23] ----
    auto pv_rand = [&](int c0) {   // c0 in {0, 4}; covers random idx c0*8 .. +31
        int jc[4];
        #pragma unroll
        for (int c = 0; c < 4; ++c)
            jc[c] = rji[(c0 + c) * 8 + gg];
        uint4 vv[4];
        #pragma unroll
        for (int c = 0; c < 4; ++c)
            vv[c] = *(const uint4*)(vb + (size_t)jc[c] * NQKV + e8);
        #pragma unroll
        for (int c = 0; c < 4; ++c) {
            float w = p[16 + c0 + c];   // 0 for invalid slots
            f32x2 w2 = {w, w};
            f32x2 p0 = {blo(vv[c].x), bhi(vv[c].x)};
            f32x2 p1 = {blo(vv[c].y), bhi(vv[c].y)};
            f32x2 p2 = {blo(vv[c].z), bhi(vv[c].z)};
            f32x2 p3 = {blo(vv[c].w), bhi(vv[c].w)};
            acc2[0] += w2 * p0;
            acc2[1] += w2 * p1;
            acc2[2] += w2 * p2;
            acc2[3] += w2 * p3;
        }
    };
    if (nval > 0)  pv_rand(0);
    if (nval > 32) pv_rand(4);

    float acc[8] = { acc2[0][0], acc2[0][1], acc2[1][0], acc2[1][1],
                     acc2[2][0], acc2[2][1], acc2[3][0], acc2[3][1] };
    // reduce across the 8 row-groups (lane bits 3,4,5) — exact R9 form
    #pragma unroll
    for (int m = 8; m <= 32; m <<= 1)
        #pragma unroll
        for (int e = 0; e < 8; ++e)
            acc[e] += __shfl_xor(acc[e], m);

    if (ln < 8) {
        float inv = 1.f / sum;
        float* op = &out[(size_t)bi * H_DIM + e8];
        *(float4*)op       = make_float4(acc[0]*inv, acc[1]*inv, acc[2]*inv, acc[3]*inv);
        *(float4*)(op + 4) = make_float4(acc[4]*inv, acc[5]*inv, acc[6]*inv, acc[7]*inv);
    }
}

// ---------------------------------------------------------------------------
extern "C" void kernel_launch(void* const* d_in, const int* in_sizes, int n_in,
                              void* d_out, int out_size, void* d_ws, size_t ws_size,
                              hipStream_t stream) {
    const float* x   = (const float*)d_in[0];
    const int*   rnd = (const int*)  d_in[1];
    const float* Wk  = (const float*)d_in[2];
    const float* Wq  = (const float*)d_in[3];
    const float* Wv  = (const float*)d_in[4];
    float* out = (float*)d_out;

    unsigned short* qkv = (unsigned short*)d_ws;             // 6,291,456 B
    int* rjc   = (int*)((char*)d_ws + 6291456);              // 524,288 B
    int* nvalb = rjc + T_DIM * 64;                           // 8,192 B

    compact_kernel<<<T_DIM / 4, 256, 0, stream>>>(rnd, rjc, nvalb);
    proj_kernel<<<M_TOTAL / 64, 512, 0, stream>>>(x, Wk, Wq, Wv, qkv);
    attn_kernel<<<M_TOTAL / 4, 256, 0, stream>>>(qkv, rjc, nvalb, out);
}

// Round 5
// 150.454 us; speedup vs baseline: 1.0091x; 1.0091x over previous
//
#include <hip/hip_runtime.h>
#include <math.h>

#define T_DIM 2048
#define C_DIM 1024
#define H_DIM 64
#define M_TOTAL 16384            // B*T
#define NQKV 192                 // k(0..63) | q(64..127) | v(128..191)

typedef __bf16 bf16x8 __attribute__((ext_vector_type(8)));
typedef float f32x4 __attribute__((ext_vector_type(4)));
typedef float f32x2 __attribute__((ext_vector_type(2)));
typedef unsigned short u16x8 __attribute__((ext_vector_type(8)));

#if __has_builtin(__builtin_amdgcn_fdot2_f32_bf16)
#define HAVE_DOT2 1
typedef __bf16 bf16x2 __attribute__((ext_vector_type(2)));
#else
#define HAVE_DOT2 0
#endif

#if __has_builtin(__builtin_amdgcn_global_load_lds)
#define HAVE_GLL 1
__device__ __forceinline__ void gload_lds16(const unsigned short* g, unsigned short* l) {
    __builtin_amdgcn_global_load_lds(
        (const __attribute__((address_space(1))) unsigned int*)(const void*)g,
        (__attribute__((address_space(3))) unsigned int*)(void*)l,
        16, 0, 0);
}
#else
#define HAVE_GLL 0
#endif

__device__ __forceinline__ unsigned short f2bf(float f) {
    unsigned u = __float_as_uint(f);
    unsigned r = (u + 0x7FFFu + ((u >> 16) & 1u)) >> 16;   // RNE
    return (unsigned short)r;
}
__device__ __forceinline__ float bf2f(unsigned short u) {
    return __uint_as_float(((unsigned)u) << 16);
}
__device__ __forceinline__ float blo(unsigned u) { return __uint_as_float(u << 16); }
__device__ __forceinline__ float bhi(unsigned u) { return __uint_as_float(u & 0xFFFF0000u); }
__device__ __forceinline__ unsigned pack_bf2(float f0, float f1) {
    unsigned u0 = __float_as_uint(f0) + 0x8000u;
    unsigned u1 = __float_as_uint(f1) + 0x8000u;
    return __builtin_amdgcn_perm(u1, u0, 0x07060302u);
}
__device__ __forceinline__ uint4 cvt8(float4 a, float4 b) {
    return make_uint4(pack_bf2(a.x, a.y), pack_bf2(a.z, a.w),
                      pack_bf2(b.x, b.y), pack_bf2(b.z, b.w));
}

// 8-elem bf16 dot: v_dot2_f32_bf16 when available, fma fallback.
__device__ __forceinline__ float dot8bf(u16x8 a, u16x8 b, float c) {
#if HAVE_DOT2
    bf16x8 av = __builtin_bit_cast(bf16x8, a);
    bf16x8 bv = __builtin_bit_cast(bf16x8, b);
    #pragma unroll
    for (int e = 0; e < 4; ++e) {
        bf16x2 ap = {av[2 * e], av[2 * e + 1]};
        bf16x2 bp = {bv[2 * e], bv[2 * e + 1]};
        c = __builtin_amdgcn_fdot2_f32_bf16(ap, bp, c, false);
    }
#else
    #pragma unroll
    for (int e = 0; e < 8; ++e) c = fmaf(bf2f(a[e]), bf2f(b[e]), c);
#endif
    return c;
}

// ---------------------------------------------------------------------------
// DPP cross-lane (VALU pipe). 0xB1=xor1, 0x4E=xor2, 0x141=row_half_mirror
// (==xor4 on 4-uniform data). Validated end-to-end by R10/R12/R13 runs.
// ---------------------------------------------------------------------------
#if __has_builtin(__builtin_amdgcn_update_dpp)
#define HAVE_DPP 1
template<int CTRL>
__device__ __forceinline__ float dppf(float x) {
    int v = __builtin_amdgcn_update_dpp(0, __builtin_bit_cast(int, x),
                                        CTRL, 0xF, 0xF, true);
    return __builtin_bit_cast(float, v);
}
__device__ __forceinline__ float red8(float p) {          // sum over 8-lane group
    p += dppf<0xB1>(p);
    p += dppf<0x4E>(p);
    p += dppf<0x141>(p);
    return p;
}
#else
#define HAVE_DPP 0
__device__ __forceinline__ float red8(float p) {
    p += __shfl_xor(p, 1); p += __shfl_xor(p, 2); p += __shfl_xor(p, 4);
    return p;
}
#endif

// ---------------------------------------------------------------------------
// Kernel W: convert Wk|Wq|Wv fp32 -> bf16, PRE-SWIZZLED within each 64-elem
// K-chunk: wbf[row][kc*64 + j] = W[row][kc*64 + (j ^ ((row&7)*8))].
// Same pack_bf2 rounding as the old in-proj conversion -> bit-identical.
// Rows: 0..63 = Wk, 64..127 = Wq, 128..191 = Wv (matches Bb order).
// ---------------------------------------------------------------------------
__global__ __launch_bounds__(256) void wconv_kernel(
    const float* __restrict__ Wk,
    const float* __restrict__ Wq,
    const float* __restrict__ Wv,
    unsigned short* __restrict__ wbf)    // [192][1024] bf16 bits
{
    int t   = blockIdx.x * 256 + threadIdx.x;    // 0..24575
    int g8  = t & 7;                             // 8-elem group in chunk
    int kc  = (t >> 3) & 15;                     // 64-elem chunk 0..15
    int row = t >> 7;                            // 0..191
    const float* src = (row < 64)  ? Wk + (size_t)row * C_DIM
                     : (row < 128) ? Wq + (size_t)(row - 64) * C_DIM
                                   : Wv + (size_t)(row - 128) * C_DIM;
    int ksrc = kc * 64 + ((g8 * 8) ^ ((row & 7) * 8));
    float4 a = *(const float4*)(src + ksrc);
    float4 b = *(const float4*)(src + ksrc + 4);
    *(uint4*)(wbf + (size_t)row * C_DIM + kc * 64 + g8 * 8) = cvt8(a, b);
}

// ---------------------------------------------------------------------------
// Kernel 0: per-row random dedup + compaction (R10-validated, unchanged).
// ---------------------------------------------------------------------------
__global__ __launch_bounds__(256) void compact_kernel(
    const int* __restrict__ rnd,          // [2048][64]
    int* __restrict__ rjc,                // [2048][64]
    int* __restrict__ nvalb)              // [2048]
{
    __shared__ unsigned bm_all[4][64];
    const int wv = threadIdx.x >> 6;
    const int ln = threadIdx.x & 63;
    const int i  = blockIdx.x * 4 + wv;
    unsigned* bm = bm_all[wv];

    bm[ln] = 0u;
    int  j2 = rnd[i * 64 + ln];
    bool v2 = (j2 < i - 63) && (j2 >= 64);
    if (v2) {   // dedup: winner of atomicOr keeps the column
        unsigned old = atomicOr(&bm[j2 >> 5], 1u << (j2 & 31));
        v2 = ((old >> (j2 & 31)) & 1u) == 0u;
    }
    unsigned long long mbal = __ballot(v2);
    const int nval = __popcll(mbal);
    if (v2) {
        int pos = __popcll(mbal & ((1ull << ln) - 1ull));
        rjc[i * 64 + pos] = j2;
    }
    if (ln >= nval) rjc[i * 64 + ln] = 0;   // safe pad (disjoint addresses)
    if (ln == 0) nvalb[i] = nval;
}

// ---------------------------------------------------------------------------
// Kernel 1: fused convert + bf16 MFMA QKV projection — R14.
// x staging unchanged (fp32 load + cvt8 + ds_write, register-dbuf prefetch).
// W staging now from pre-converted bf16 wbf via global_load_lds width=16:
// linear LDS dest (wave base + lane*16), swizzle baked into wbf's layout.
// W L2 traffic halves (bf16); 3/4 of staging VALU + registers removed.
// MFMA consume loop and C-write identical to the validated form.
// ---------------------------------------------------------------------------
__global__ __launch_bounds__(512) void proj_kernel(
    const float* __restrict__ x,
    const unsigned short* __restrict__ wbf,   // [192][1024] bf16 pre-swizzled
    unsigned short* __restrict__ qkv)         // [16384][192] bf16 bits
{
    __shared__ unsigned short Ab[64 * 64];    // [row][k^swz]
    __shared__ unsigned short Bb[192 * 64];   // [col][k^swz]

    const int m0 = blockIdx.x * 64;
    const int t  = threadIdx.x;
    const int wv = t >> 6, ln = t & 63;
    const int mfr = ln & 15, kq = ln >> 4;
    const int r0 = (wv & 1) * 32;
    const int c0 = (wv >> 1) * 48;

    const int srow  = t >> 3;                // 0..63
    const int sk8   = (t & 7) * 8;
    const int skoff = sk8 ^ ((srow & 7) * 8);

    const float* gpx = x + (size_t)(m0 + srow) * C_DIM + sk8;
    unsigned short* lpx = &Ab[srow * 64 + skoff];

    // W staging geometry: issue s covers rows s*64 + wv*8 .. +7; lane ln
    // reads wbf[row][kc + (ln&7)*8], row = s*64 + wv*8 + (ln>>3).
    const int wrow = wv * 8 + (ln >> 3);
    const unsigned short* wsrc = wbf + (size_t)wrow * C_DIM + (ln & 7) * 8;

    f32x4 acc[2][3] = {};

    float4 ra = *(const float4*)(gpx);
    float4 rb = *(const float4*)(gpx + 4);

    for (int kc = 0; kc < C_DIM; kc += 64) {
        __syncthreads();
        *(uint4*)lpx = cvt8(ra, rb);
#if HAVE_GLL
        #pragma unroll
        for (int s = 0; s < 3; ++s)
            gload_lds16(wsrc + (size_t)s * 64 * C_DIM + kc,
                        &Bb[(s * 64 + wv * 8) * 64]);
#else
        #pragma unroll
        for (int s = 0; s < 3; ++s) {
            uint4 w4 = *(const uint4*)(wsrc + (size_t)s * 64 * C_DIM + kc);
            *(uint4*)&Bb[(s * 64 + wv * 8 + (ln >> 3)) * 64 + (ln & 7) * 8] = w4;
        }
#endif
        if (kc + 64 < C_DIM) {
            ra = *(const float4*)(gpx + kc + 64);
            rb = *(const float4*)(gpx + kc + 68);
        }
        __syncthreads();   // drains lgkm + vmcnt -> Ab/Bb ready
        #pragma unroll
        for (int ks = 0; ks < 64; ks += 32) {
            bf16x8 af[2], bf[3];
            #pragma unroll
            for (int a = 0; a < 2; ++a) {
                int row = r0 + a * 16 + mfr;
                af[a] = *(const bf16x8*)&Ab[row * 64 + ((ks + kq * 8) ^ ((row & 7) * 8))];
            }
            #pragma unroll
            for (int b2 = 0; b2 < 3; ++b2) {
                int row = c0 + b2 * 16 + mfr;
                bf[b2] = *(const bf16x8*)&Bb[row * 64 + ((ks + kq * 8) ^ ((row & 7) * 8))];
            }
            #pragma unroll
            for (int a = 0; a < 2; ++a)
                #pragma unroll
                for (int b2 = 0; b2 < 3; ++b2)
                    acc[a][b2] = __builtin_amdgcn_mfma_f32_16x16x32_bf16(
                        af[a], bf[b2], acc[a][b2], 0, 0, 0);
        }
    }

    #pragma unroll
    for (int a = 0; a < 2; ++a)
        #pragma unroll
        for (int b2 = 0; b2 < 3; ++b2)
            #pragma unroll
            for (int r = 0; r < 4; ++r) {
                int row = m0 + r0 + a * 16 + kq * 4 + r;
                int col = c0 + b2 * 16 + mfr;
                qkv[(size_t)row * NQKV + col] = f2bf(acc[a][b2][r]);
            }
}

// ---------------------------------------------------------------------------
// Kernel 2: sparse BigBird attention — R14: wide-issue gather batches.
// R13 structure (register-resident scores, no LDS, R9 gather layout) with
// ILP widened: all 16 fixed K-gathers issued before any consume; rand-K as
// ONE 8-wide batch (guard nval>0 only — pad slots load col 0 and are masked
// to weight 0, values identical to R13); all 16 fixed V-gathers issued
// BEFORE softmax so their latency hides under the softmax VALU; rand-V as
// one 8-wide guarded batch. Masks/numerics bit-identical to R13 (passed).
// ---------------------------------------------------------------------------
__global__ __launch_bounds__(256) void attn_kernel(
    const unsigned short* __restrict__ qkv,   // bf16 bits [16384][192]
    const int*  __restrict__ rjc,             // [2048][64] compacted randoms
    const int*  __restrict__ nvalb,           // [2048]
    float* __restrict__ out)                  // [16384][64]
{
    const int wv = threadIdx.x >> 6;
    const int ln = threadIdx.x & 63;
    const int b  = blockIdx.x & 7;                  // XCD-locality swizzle
    const int i  = ((blockIdx.x >> 3) << 2) + wv;   // 0..2047
    const int bi = b * T_DIM + i;

    const int  nval = nvalb[i];                     // wave-uniform
    const int* rji  = rjc + i * 64;

    // ---- layout: gg = ln>>3 row-group (HIGH bits of slot), 8 lanes/row ----
    const int e8 = (ln & 7) * 8;     // h-slice base for this lane
    const int gg = ln >> 3;          // row-group 0..7
    u16x8 qraw = *(const u16x8*)(qkv + (size_t)bi * NQKV + 64 + e8);
    const unsigned short* kb = qkv + (size_t)b * T_DIM * NQKV;
    const unsigned short* vb = kb + 128;

    float p[24];

    // ---- QK fixed: issue ALL 16 gathers, then consume ----
    u16x8 kf[16];
    #pragma unroll
    for (int n = 0; n < 16; ++n) {
        int s = n * 8 + gg;
        int j;
        if (s < 64) { j = i - s; j = (j < 0) ? 0 : j; }
        else        { j = s - 64; }
        kf[n] = *(const u16x8*)(kb + (size_t)j * NQKV + e8);
    }
    #pragma unroll
    for (int n = 0; n < 16; ++n)
        p[n] = red8(dot8bf(kf[n], qraw, 0.f));

    // ---- QK rand: ONE 8-wide batch, wave-uniform guard ----
    if (nval > 0) {
        u16x8 kr[8];
        #pragma unroll
        for (int u = 0; u < 8; ++u)
            kr[u] = *(const u16x8*)(kb + (size_t)rji[u * 8 + gg] * NQKV + e8);
        #pragma unroll
        for (int u = 0; u < 8; ++u)
            p[16 + u] = red8(dot8bf(kr[u], qraw, 0.f));
    } else {
        #pragma unroll
        for (int u = 0; u < 8; ++u) p[16 + u] = 0.f;
    }

    // ---- issue ALL 16 fixed V-gathers before softmax (indices independent) ----
    uint4 vf[16];
    #pragma unroll
    for (int n = 0; n < 16; ++n) {
        int s = n * 8 + gg;
        int j;
        if (s < 64) { j = i - s; j = (j < 0) ? 0 : j; }
        else        { j = s - 64; }
        vf[n] = *(const uint4*)(vb + (size_t)j * NQKV + e8);
    }

    // ---- mask + scale in place (invalid -> -1e30) ----
    #pragma unroll
    for (int idx = 0; idx < 8; ++idx) {
        bool v = (idx * 8 + gg) <= i;               // local col i-s >= 0
        p[idx] = v ? p[idx] * 0.125f : -1e30f;
    }
    #pragma unroll
    for (int idx = 8; idx < 16; ++idx) {
        bool v = ((idx - 8) * 8 + gg) < (i - 63);   // global col < i-63
        p[idx] = v ? p[idx] * 0.125f : -1e30f;
    }
    #pragma unroll
    for (int idx = 16; idx < 24; ++idx) {
        bool v = ((idx - 16) * 8 + gg) < nval;      // compacted random valid
        p[idx] = v ? p[idx] * 0.125f : -1e30f;
    }

    // ---- softmax, fully in-register + 3 shfl per reduction ----
    float mx = p[0];
    #pragma unroll
    for (int idx = 1; idx < 24; ++idx) mx = fmaxf(mx, p[idx]);
    mx = fmaxf(mx, __shfl_xor(mx, 8));
    mx = fmaxf(mx, __shfl_xor(mx, 16));
    mx = fmaxf(mx, __shfl_xor(mx, 32));

    float sum = 0.f;
    #pragma unroll
    for (int idx = 0; idx < 24; ++idx) {
        p[idx] = __expf(p[idx] - mx);   // masked slots underflow to exact 0
        sum += p[idx];
    }
    sum += __shfl_xor(sum, 8);
    sum += __shfl_xor(sum, 16);
    sum += __shfl_xor(sum, 32);

    // ---- PV fixed: consume the pre-issued 16 V rows ----
    f32x2 acc2[4] = {};
    #pragma unroll
    for (int n = 0; n < 16; ++n) {
        float w = p[n];
        f32x2 w2 = {w, w};
        f32x2 p0 = {blo(vf[n].x), bhi(vf[n].x)};
        f32x2 p1 = {blo(vf[n].y), bhi(vf[n].y)};
        f32x2 p2 = {blo(vf[n].z), bhi(vf[n].z)};
        f32x2 p3 = {blo(vf[n].w), bhi(vf[n].w)};
        acc2[0] += w2 * p0;
        acc2[1] += w2 * p1;
        acc2[2] += w2 * p2;
        acc2[3] += w2 * p3;
    }

    // ---- PV rand: ONE 8-wide guarded batch (weights 0 for pad slots) ----
    if (nval > 0) {
        uint4 vr[8];
        #pragma unroll
        for (int u = 0; u < 8; ++u)
            vr[u] = *(const uint4*)(vb + (size_t)rji[u * 8 + gg] * NQKV + e8);
        #pragma unroll
        for (int u = 0; u < 8; ++u) {
            float w = p[16 + u];
            f32x2 w2 = {w, w};
            f32x2 p0 = {blo(vr[u].x), bhi(vr[u].x)};
            f32x2 p1 = {blo(vr[u].y), bhi(vr[u].y)};
            f32x2 p2 = {blo(vr[u].z), bhi(vr[u].z)};
            f32x2 p3 = {blo(vr[u].w), bhi(vr[u].w)};
            acc2[0] += w2 * p0;
            acc2[1] += w2 * p1;
            acc2[2] += w2 * p2;
            acc2[3] += w2 * p3;
        }
    }

    float acc[8] = { acc2[0][0], acc2[0][1], acc2[1][0], acc2[1][1],
                     acc2[2][0], acc2[2][1], acc2[3][0], acc2[3][1] };
    // reduce across the 8 row-groups (lane bits 3,4,5) — exact R9 form
    #pragma unroll
    for (int m = 8; m <= 32; m <<= 1)
        #pragma unroll
        for (int e = 0; e < 8; ++e)
            acc[e] += __shfl_xor(acc[e], m);

    if (ln < 8) {
        float inv = 1.f / sum;
        float* op = &out[(size_t)bi * H_DIM + e8];
        *(float4*)op       = make_float4(acc[0]*inv, acc[1]*inv, acc[2]*inv, acc[3]*inv);
        *(float4*)(op + 4) = make_float4(acc[4]*inv, acc[5]*inv, acc[6]*inv, acc[7]*inv);
    }
}

// ---------------------------------------------------------------------------
extern "C" void kernel_launch(void* const* d_in, const int* in_sizes, int n_in,
                              void* d_out, int out_size, void* d_ws, size_t ws_size,
                              hipStream_t stream) {
    const float* x   = (const float*)d_in[0];
    const int*   rnd = (const int*)  d_in[1];
    const float* Wk  = (const float*)d_in[2];
    const float* Wq  = (const float*)d_in[3];
    const float* Wv  = (const float*)d_in[4];
    float* out = (float*)d_out;

    unsigned short* qkv = (unsigned short*)d_ws;             // 6,291,456 B
    int* rjc   = (int*)((char*)d_ws + 6291456);              // 524,288 B
    int* nvalb = rjc + T_DIM * 64;                           // 8,192 B
    unsigned short* wbf = (unsigned short*)((char*)d_ws + 6823936);  // 393,216 B

    wconv_kernel<<<96, 256, 0, stream>>>(Wk, Wq, Wv, wbf);
    compact_kernel<<<T_DIM / 4, 256, 0, stream>>>(rnd, rjc, nvalb);
    proj_kernel<<<M_TOTAL / 64, 512, 0, stream>>>(x, wbf, qkv);
    attn_kernel<<<M_TOTAL / 4, 256, 0, stream>>>(qkv, rjc, nvalb, out);
}

// Round 6
// 145.981 us; speedup vs baseline: 1.0400x; 1.0306x over previous
//
#include <hip/hip_runtime.h>
#include <math.h>

#define T_DIM 2048
#define C_DIM 1024
#define H_DIM 64
#define M_TOTAL 16384            // B*T
#define NQKV 192                 // k(0..63) | q(64..127) | v(128..191)

typedef __bf16 bf16x8 __attribute__((ext_vector_type(8)));
typedef float f32x4 __attribute__((ext_vector_type(4)));
typedef float f32x2 __attribute__((ext_vector_type(2)));
typedef unsigned short u16x8 __attribute__((ext_vector_type(8)));

#if __has_builtin(__builtin_amdgcn_fdot2_f32_bf16)
#define HAVE_DOT2 1
typedef __bf16 bf16x2 __attribute__((ext_vector_type(2)));
#else
#define HAVE_DOT2 0
#endif

#if __has_builtin(__builtin_amdgcn_global_load_lds)
#define HAVE_GLL 1
__device__ __forceinline__ void gload_lds16(const unsigned short* g, unsigned short* l) {
    __builtin_amdgcn_global_load_lds(
        (const __attribute__((address_space(1))) unsigned int*)(const void*)g,
        (__attribute__((address_space(3))) unsigned int*)(void*)l,
        16, 0, 0);
}
#else
#define HAVE_GLL 0
#endif

__device__ __forceinline__ unsigned short f2bf(float f) {
    unsigned u = __float_as_uint(f);
    unsigned r = (u + 0x7FFFu + ((u >> 16) & 1u)) >> 16;   // RNE
    return (unsigned short)r;
}
__device__ __forceinline__ float bf2f(unsigned short u) {
    return __uint_as_float(((unsigned)u) << 16);
}
__device__ __forceinline__ float blo(unsigned u) { return __uint_as_float(u << 16); }
__device__ __forceinline__ float bhi(unsigned u) { return __uint_as_float(u & 0xFFFF0000u); }
__device__ __forceinline__ unsigned pack_bf2(float f0, float f1) {
    unsigned u0 = __float_as_uint(f0) + 0x8000u;
    unsigned u1 = __float_as_uint(f1) + 0x8000u;
    return __builtin_amdgcn_perm(u1, u0, 0x07060302u);
}
__device__ __forceinline__ uint4 cvt8(float4 a, float4 b) {
    return make_uint4(pack_bf2(a.x, a.y), pack_bf2(a.z, a.w),
                      pack_bf2(b.x, b.y), pack_bf2(b.z, b.w));
}

// 8-elem bf16 dot: v_dot2_f32_bf16 when available, fma fallback.
__device__ __forceinline__ float dot8bf(u16x8 a, u16x8 b, float c) {
#if HAVE_DOT2
    bf16x8 av = __builtin_bit_cast(bf16x8, a);
    bf16x8 bv = __builtin_bit_cast(bf16x8, b);
    #pragma unroll
    for (int e = 0; e < 4; ++e) {
        bf16x2 ap = {av[2 * e], av[2 * e + 1]};
        bf16x2 bp = {bv[2 * e], bv[2 * e + 1]};
        c = __builtin_amdgcn_fdot2_f32_bf16(ap, bp, c, false);
    }
#else
    #pragma unroll
    for (int e = 0; e < 8; ++e) c = fmaf(bf2f(a[e]), bf2f(b[e]), c);
#endif
    return c;
}

// ---------------------------------------------------------------------------
// DPP cross-lane (VALU pipe). 0xB1=xor1, 0x4E=xor2, 0x141=row_half_mirror
// (==xor4 on 4-uniform data). Validated end-to-end by R10/R12/R13/R14 runs.
// ---------------------------------------------------------------------------
#if __has_builtin(__builtin_amdgcn_update_dpp)
#define HAVE_DPP 1
template<int CTRL>
__device__ __forceinline__ float dppf(float x) {
    int v = __builtin_amdgcn_update_dpp(0, __builtin_bit_cast(int, x),
                                        CTRL, 0xF, 0xF, true);
    return __builtin_bit_cast(float, v);
}
__device__ __forceinline__ float red8(float p) {          // sum over 8-lane group
    p += dppf<0xB1>(p);
    p += dppf<0x4E>(p);
    p += dppf<0x141>(p);
    return p;
}
#else
#define HAVE_DPP 0
__device__ __forceinline__ float red8(float p) {
    p += __shfl_xor(p, 1); p += __shfl_xor(p, 2); p += __shfl_xor(p, 4);
    return p;
}
#endif

// ---------------------------------------------------------------------------
// Kernel W: convert Wk|Wq|Wv fp32 -> bf16, PRE-SWIZZLED within each 64-elem
// K-chunk (unchanged from R14, validated).
// ---------------------------------------------------------------------------
__global__ __launch_bounds__(256) void wconv_kernel(
    const float* __restrict__ Wk,
    const float* __restrict__ Wq,
    const float* __restrict__ Wv,
    unsigned short* __restrict__ wbf)    // [192][1024] bf16 bits
{
    int t   = blockIdx.x * 256 + threadIdx.x;    // 0..24575
    int g8  = t & 7;                             // 8-elem group in chunk
    int kc  = (t >> 3) & 15;                     // 64-elem chunk 0..15
    int row = t >> 7;                            // 0..191
    const float* src = (row < 64)  ? Wk + (size_t)row * C_DIM
                     : (row < 128) ? Wq + (size_t)(row - 64) * C_DIM
                                   : Wv + (size_t)(row - 128) * C_DIM;
    int ksrc = kc * 64 + ((g8 * 8) ^ ((row & 7) * 8));
    float4 a = *(const float4*)(src + ksrc);
    float4 b = *(const float4*)(src + ksrc + 4);
    *(uint4*)(wbf + (size_t)row * C_DIM + kc * 64 + g8 * 8) = cvt8(a, b);
}

// ---------------------------------------------------------------------------
// Kernel 0: per-row random dedup + compaction (R10-validated, unchanged).
// ---------------------------------------------------------------------------
__global__ __launch_bounds__(256) void compact_kernel(
    const int* __restrict__ rnd,          // [2048][64]
    int* __restrict__ rjc,                // [2048][64]
    int* __restrict__ nvalb)              // [2048]
{
    __shared__ unsigned bm_all[4][64];
    const int wv = threadIdx.x >> 6;
    const int ln = threadIdx.x & 63;
    const int i  = blockIdx.x * 4 + wv;
    unsigned* bm = bm_all[wv];

    bm[ln] = 0u;
    int  j2 = rnd[i * 64 + ln];
    bool v2 = (j2 < i - 63) && (j2 >= 64);
    if (v2) {   // dedup: winner of atomicOr keeps the column
        unsigned old = atomicOr(&bm[j2 >> 5], 1u << (j2 & 31));
        v2 = ((old >> (j2 & 31)) & 1u) == 0u;
    }
    unsigned long long mbal = __ballot(v2);
    const int nval = __popcll(mbal);
    if (v2) {
        int pos = __popcll(mbal & ((1ull << ln) - 1ull));
        rjc[i * 64 + pos] = j2;
    }
    if (ln >= nval) rjc[i * 64 + ln] = 0;   // safe pad (disjoint addresses)
    if (ln == 0) nvalb[i] = nval;
}

// ---------------------------------------------------------------------------
// Kernel 1: fused convert + bf16 MFMA QKV projection (R14, validated).
// ---------------------------------------------------------------------------
__global__ __launch_bounds__(512) void proj_kernel(
    const float* __restrict__ x,
    const unsigned short* __restrict__ wbf,   // [192][1024] bf16 pre-swizzled
    unsigned short* __restrict__ qkv)         // [16384][192] bf16 bits
{
    __shared__ unsigned short Ab[64 * 64];    // [row][k^swz]
    __shared__ unsigned short Bb[192 * 64];   // [col][k^swz]

    const int m0 = blockIdx.x * 64;
    const int t  = threadIdx.x;
    const int wv = t >> 6, ln = t & 63;
    const int mfr = ln & 15, kq = ln >> 4;
    const int r0 = (wv & 1) * 32;
    const int c0 = (wv >> 1) * 48;

    const int srow  = t >> 3;                // 0..63
    const int sk8   = (t & 7) * 8;
    const int skoff = sk8 ^ ((srow & 7) * 8);

    const float* gpx = x + (size_t)(m0 + srow) * C_DIM + sk8;
    unsigned short* lpx = &Ab[srow * 64 + skoff];

    const int wrow = wv * 8 + (ln >> 3);
    const unsigned short* wsrc = wbf + (size_t)wrow * C_DIM + (ln & 7) * 8;

    f32x4 acc[2][3] = {};

    float4 ra = *(const float4*)(gpx);
    float4 rb = *(const float4*)(gpx + 4);

    for (int kc = 0; kc < C_DIM; kc += 64) {
        __syncthreads();
        *(uint4*)lpx = cvt8(ra, rb);
#if HAVE_GLL
        #pragma unroll
        for (int s = 0; s < 3; ++s)
            gload_lds16(wsrc + (size_t)s * 64 * C_DIM + kc,
                        &Bb[(s * 64 + wv * 8) * 64]);
#else
        #pragma unroll
        for (int s = 0; s < 3; ++s) {
            uint4 w4 = *(const uint4*)(wsrc + (size_t)s * 64 * C_DIM + kc);
            *(uint4*)&Bb[(s * 64 + wv * 8 + (ln >> 3)) * 64 + (ln & 7) * 8] = w4;
        }
#endif
        if (kc + 64 < C_DIM) {
            ra = *(const float4*)(gpx + kc + 64);
            rb = *(const float4*)(gpx + kc + 68);
        }
        __syncthreads();   // drains lgkm + vmcnt -> Ab/Bb ready
        #pragma unroll
        for (int ks = 0; ks < 64; ks += 32) {
            bf16x8 af[2], bf[3];
            #pragma unroll
            for (int a = 0; a < 2; ++a) {
                int row = r0 + a * 16 + mfr;
                af[a] = *(const bf16x8*)&Ab[row * 64 + ((ks + kq * 8) ^ ((row & 7) * 8))];
            }
            #pragma unroll
            for (int b2 = 0; b2 < 3; ++b2) {
                int row = c0 + b2 * 16 + mfr;
                bf[b2] = *(const bf16x8*)&Bb[row * 64 + ((ks + kq * 8) ^ ((row & 7) * 8))];
            }
            #pragma unroll
            for (int a = 0; a < 2; ++a)
                #pragma unroll
                for (int b2 = 0; b2 < 3; ++b2)
                    acc[a][b2] = __builtin_amdgcn_mfma_f32_16x16x32_bf16(
                        af[a], bf[b2], acc[a][b2], 0, 0, 0);
        }
    }

    #pragma unroll
    for (int a = 0; a < 2; ++a)
        #pragma unroll
        for (int b2 = 0; b2 < 3; ++b2)
            #pragma unroll
            for (int r = 0; r < 4; ++r) {
                int row = m0 + r0 + a * 16 + kq * 4 + r;
                int col = c0 + b2 * 16 + mfr;
                qkv[(size_t)row * NQKV + col] = f2bf(acc[a][b2][r]);
            }
}

// ---------------------------------------------------------------------------
// Kernel 2: sparse BigBird attention — R15: block-level K/V staging.
// Block = 512 threads = 8 waves = 8 consecutive queries i0..i0+7. The fixed
// slots (local window + global cols) of these queries overlap massively:
// stage their union ONCE in LDS and read fixed K/V via ds_read_b128.
//   st rows 0..134   : K slices. t'<71: col = max(i0-63+t',0) (local union;
//                      clamp matches the old per-query j=max(i-s,0) garbage
//                      source bit-exactly). t'>=71: col = t'-71 (global).
//   st rows 135..269 : V slices, same mapping.
// For query q=i-i0, local slot s -> idx q+63-s (in [q,q+63] subset [0,70]);
// global slot s -> idx s+7 (in [71,134]). Fixed-slot L2 traffic drops
// 524 MB -> 71 MB. Randoms / Q / masks / softmax / reduce / store are the
// R13/R14-validated code, unchanged. Numerics bit-identical.
// ---------------------------------------------------------------------------
__global__ __launch_bounds__(512) void attn_kernel(
    const unsigned short* __restrict__ qkv,   // bf16 bits [16384][192]
    const int*  __restrict__ rjc,             // [2048][64] compacted randoms
    const int*  __restrict__ nvalb,           // [2048]
    float* __restrict__ out)                  // [16384][64]
{
    __shared__ unsigned short st[270 * 64];   // 34,560 B

    const int t  = threadIdx.x;
    const int wv = t >> 6;                          // 0..7
    const int ln = t & 63;
    const int b  = blockIdx.x & 7;                  // XCD-locality swizzle
    const int qb = blockIdx.x >> 3;                 // 0..255
    const int i0 = qb * 8;
    const int i  = i0 + wv;                         // 0..2047
    const int bi = b * T_DIM + i;

    const unsigned short* kb = qkv + (size_t)b * T_DIM * NQKV;
    const unsigned short* vb = kb + 128;

    // ---- cooperative staging: 270 rows x 128B, 8 threads per row ----
    {
        const int l8 = t & 7;
        #pragma unroll
        for (int p = 0; p < 5; ++p) {
            int si = p * 64 + (t >> 3);             // 0..319
            if (si < 270) {
                int tp  = (si < 135) ? si : si - 135;
                int col = (tp < 71) ? max(i0 - 63 + tp, 0) : tp - 71;
                const unsigned short* src =
                    ((si < 135) ? kb : vb) + (size_t)col * NQKV + l8 * 8;
                *(uint4*)&st[si * 64 + l8 * 8] = *(const uint4*)src;
            }
        }
    }
    __syncthreads();

    const int  nval = nvalb[i];                     // wave-uniform
    const int* rji  = rjc + i * 64;

    const int e8 = (ln & 7) * 8;     // h-slice base for this lane
    const int gg = ln >> 3;          // row-group 0..7
    const int q  = wv;               // i - i0
    u16x8 qraw = *(const u16x8*)(qkv + (size_t)bi * NQKV + 64 + e8);

    float p[24];

    // ---- QK fixed: 16 slot-groups from LDS ----
    #pragma unroll
    for (int n = 0; n < 16; n += 4) {
        u16x8 kf[4];
        #pragma unroll
        for (int u = 0; u < 4; ++u) {
            int s   = (n + u) * 8 + gg;
            int idx = (s < 64) ? (q + 63 - s) : (s + 7);
            kf[u] = *(const u16x8*)&st[idx * 64 + e8];
        }
        #pragma unroll
        for (int u = 0; u < 4; ++u)
            p[n + u] = red8(dot8bf(kf[u], qraw, 0.f));
    }

    // ---- QK rand: ONE 8-wide batch from global, wave-uniform guard ----
    if (nval > 0) {
        u16x8 kr[8];
        #pragma unroll
        for (int u = 0; u < 8; ++u)
            kr[u] = *(const u16x8*)(kb + (size_t)rji[u * 8 + gg] * NQKV + e8);
        #pragma unroll
        for (int u = 0; u < 8; ++u)
            p[16 + u] = red8(dot8bf(kr[u], qraw, 0.f));
    } else {
        #pragma unroll
        for (int u = 0; u < 8; ++u) p[16 + u] = 0.f;
    }

    // ---- mask + scale in place (invalid -> -1e30), R13 form ----
    #pragma unroll
    for (int idx = 0; idx < 8; ++idx) {
        bool v = (idx * 8 + gg) <= i;               // local col i-s >= 0
        p[idx] = v ? p[idx] * 0.125f : -1e30f;
    }
    #pragma unroll
    for (int idx = 8; idx < 16; ++idx) {
        bool v = ((idx - 8) * 8 + gg) < (i - 63);   // global col < i-63
        p[idx] = v ? p[idx] * 0.125f : -1e30f;
    }
    #pragma unroll
    for (int idx = 16; idx < 24; ++idx) {
        bool v = ((idx - 16) * 8 + gg) < nval;      // compacted random valid
        p[idx] = v ? p[idx] * 0.125f : -1e30f;
    }

    // ---- softmax, fully in-register + 3 shfl per reduction ----
    float mx = p[0];
    #pragma unroll
    for (int idx = 1; idx < 24; ++idx) mx = fmaxf(mx, p[idx]);
    mx = fmaxf(mx, __shfl_xor(mx, 8));
    mx = fmaxf(mx, __shfl_xor(mx, 16));
    mx = fmaxf(mx, __shfl_xor(mx, 32));

    float sum = 0.f;
    #pragma unroll
    for (int idx = 0; idx < 24; ++idx) {
        p[idx] = __expf(p[idx] - mx);   // masked slots underflow to exact 0
        sum += p[idx];
    }
    sum += __shfl_xor(sum, 8);
    sum += __shfl_xor(sum, 16);
    sum += __shfl_xor(sum, 32);

    // ---- PV fixed: 16 slot-groups from LDS ----
    f32x2 acc2[4] = {};
    #pragma unroll
    for (int n = 0; n < 16; n += 4) {
        uint4 vf[4];
        #pragma unroll
        for (int u = 0; u < 4; ++u) {
            int s   = (n + u) * 8 + gg;
            int idx = (s < 64) ? (q + 63 - s) : (s + 7);
            vf[u] = *(const uint4*)&st[(135 + idx) * 64 + e8];
        }
        #pragma unroll
        for (int u = 0; u < 4; ++u) {
            float w = p[n + u];
            f32x2 w2 = {w, w};
            f32x2 p0 = {blo(vf[u].x), bhi(vf[u].x)};
            f32x2 p1 = {blo(vf[u].y), bhi(vf[u].y)};
            f32x2 p2 = {blo(vf[u].z), bhi(vf[u].z)};
            f32x2 p3 = {blo(vf[u].w), bhi(vf[u].w)};
            acc2[0] += w2 * p0;
            acc2[1] += w2 * p1;
            acc2[2] += w2 * p2;
            acc2[3] += w2 * p3;
        }
    }

    // ---- PV rand: ONE 8-wide guarded batch from global ----
    if (nval > 0) {
        uint4 vr[8];
        #pragma unroll
        for (int u = 0; u < 8; ++u)
            vr[u] = *(const uint4*)(vb + (size_t)rji[u * 8 + gg] * NQKV + e8);
        #pragma unroll
        for (int u = 0; u < 8; ++u) {
            float w = p[16 + u];
            f32x2 w2 = {w, w};
            f32x2 p0 = {blo(vr[u].x), bhi(vr[u].x)};
            f32x2 p1 = {blo(vr[u].y), bhi(vr[u].y)};
            f32x2 p2 = {blo(vr[u].z), bhi(vr[u].z)};
            f32x2 p3 = {blo(vr[u].w), bhi(vr[u].w)};
            acc2[0] += w2 * p0;
            acc2[1] += w2 * p1;
            acc2[2] += w2 * p2;
            acc2[3] += w2 * p3;
        }
    }

    float acc[8] = { acc2[0][0], acc2[0][1], acc2[1][0], acc2[1][1],
                     acc2[2][0], acc2[2][1], acc2[3][0], acc2[3][1] };
    // reduce across the 8 row-groups (lane bits 3,4,5) — exact R9 form
    #pragma unroll
    for (int m = 8; m <= 32; m <<= 1)
        #pragma unroll
        for (int e = 0; e < 8; ++e)
            acc[e] += __shfl_xor(acc[e], m);

    if (ln < 8) {
        float inv = 1.f / sum;
        float* op = &out[(size_t)bi * H_DIM + e8];
        *(float4*)op       = make_float4(acc[0]*inv, acc[1]*inv, acc[2]*inv, acc[3]*inv);
        *(float4*)(op + 4) = make_float4(acc[4]*inv, acc[5]*inv, acc[6]*inv, acc[7]*inv);
    }
}

// ---------------------------------------------------------------------------
extern "C" void kernel_launch(void* const* d_in, const int* in_sizes, int n_in,
                              void* d_out, int out_size, void* d_ws, size_t ws_size,
                              hipStream_t stream) {
    const float* x   = (const float*)d_in[0];
    const int*   rnd = (const int*)  d_in[1];
    const float* Wk  = (const float*)d_in[2];
    const float* Wq  = (const float*)d_in[3];
    const float* Wv  = (const float*)d_in[4];
    float* out = (float*)d_out;

    unsigned short* qkv = (unsigned short*)d_ws;             // 6,291,456 B
    int* rjc   = (int*)((char*)d_ws + 6291456);              // 524,288 B
    int* nvalb = rjc + T_DIM * 64;                           // 8,192 B
    unsigned short* wbf = (unsigned short*)((char*)d_ws + 6823936);  // 393,216 B

    wconv_kernel<<<96, 256, 0, stream>>>(Wk, Wq, Wv, wbf);
    compact_kernel<<<T_DIM / 4, 256, 0, stream>>>(rnd, rjc, nvalb);
    proj_kernel<<<M_TOTAL / 64, 512, 0, stream>>>(x, wbf, qkv);
    attn_kernel<<<M_TOTAL / 8, 512, 0, stream>>>(qkv, rjc, nvalb, out);
}